// Round 5
// baseline (2009.214 us; speedup 1.0000x reference)
//
#include <hip/hip_runtime.h>
#include <hip/hip_bf16.h>
#include <stdint.h>

typedef unsigned short u16;
typedef unsigned int u32;
typedef unsigned long long u64;
typedef __attribute__((ext_vector_type(4))) float f32x4;
typedef __attribute__((ext_vector_type(8))) short s16x8;

#define AT_LD(p)    __hip_atomic_load((p), __ATOMIC_RELAXED, __HIP_MEMORY_SCOPE_AGENT)
#define AT_ST(p, v) __hip_atomic_store((p), (v), __ATOMIC_RELAXED, __HIP_MEMORY_SCOPE_AGENT)

// ---------- helpers ----------

static __device__ __forceinline__ u16 f2bf(float f) {
  union { float f; unsigned u; } v; v.f = f;
  unsigned r = v.u + 0x7FFFu + ((v.u >> 16) & 1u);
  return (u16)(r >> 16);
}

static __device__ __forceinline__ void gload_lds16(const void* g, void* l) {
  __builtin_amdgcn_global_load_lds(
      (const __attribute__((address_space(1))) unsigned int*)(uintptr_t)g,
      (__attribute__((address_space(3))) unsigned int*)(uintptr_t)l,
      16, 0, 0);
}

// ---------- pre-pass kernels ----------

__global__ void embed_kernel(const int* __restrict__ inputs,
                             const float* __restrict__ emb,
                             u16* __restrict__ xbf) {
  int i = blockIdx.x * 256 + threadIdx.x;   // 131072 threads
  int row = i >> 6;
  int e0 = (i & 63) << 3;
  int tok = inputs[row];
  const float* src = emb + (size_t)tok * 512 + e0;
  s16x8 o;
#pragma unroll
  for (int j = 0; j < 8; ++j) o[j] = (short)f2bf(src[j]);
  *(s16x8*)(xbf + (size_t)row * 512 + e0) = o;
}

// bit-pack mask: maskb[b*2+h] bit j = (inputs[b*128 + h*64 + j] != 0)
__global__ void mask_kernel(const int* __restrict__ inputs, u64* __restrict__ mb) {
  int t = threadIdx.x;
  if (t < 32) {
    int b = t >> 1, h = t & 1;
    u64 m = 0;
    for (int j = 0; j < 64; ++j)
      m |= (u64)(inputs[b * 128 + h * 64 + j] != 0) << j;
    mb[t] = m;
  }
}

// Wt[n][k] = bf16(W[k][n]); K,N multiples of 32
__global__ void transpose_bf16(const float* __restrict__ W, u16* __restrict__ Wt,
                               int K, int N) {
  __shared__ float t[32][33];
  int ntn = N >> 5;
  int tn = blockIdx.x % ntn, tk = blockIdx.x / ntn;
  int n0 = tn << 5, k0 = tk << 5;
  int tx = threadIdx.x & 31, ty = threadIdx.x >> 5;  // ty 0..7
#pragma unroll
  for (int j = 0; j < 4; ++j) {
    int k = ty * 4 + j;
    t[k][tx] = W[(size_t)(k0 + k) * N + n0 + tx];
  }
  __syncthreads();
#pragma unroll
  for (int j = 0; j < 4; ++j) {
    int n = ty * 4 + j;
    Wt[(size_t)(n0 + n) * K + k0 + tx] = f2bf(t[tx][n]);
  }
}

// ---------- m97-style bf16 GEMM, 128x128 tile, BK=32 ----------
// MODE 0: C=f32, store acc+bias          (xg)
// MODE 1: C=bf16, store relu(acc+bias)   (d1)
// MODE 2: C=f32, store exp(acc+bias), atomicAdd row sums (logits->exp)
template <int MODE>
__global__ __launch_bounds__(256)
void gemm_bf16(const u16* __restrict__ A, const u16* __restrict__ Bt,
               const float* __restrict__ bias, void* __restrict__ Cptr,
               float* __restrict__ rowsum, int M, int N, int K) {
  (void)M;
  __shared__ u16 sA[128 * 32];
  __shared__ u16 sB[128 * 32];
  const int nbn = N >> 7;
  const int nwg = gridDim.x;
  int bid = blockIdx.x;
  int q = nwg >> 3;                         // grids are multiples of 8
  int swz = (bid & 7) * q + (bid >> 3);     // XCD-aware swizzle (bijective)
  int bm = swz / nbn, bn = swz % nbn;
  const int brow = bm << 7, bcol = bn << 7;

  const int tid = threadIdx.x;
  const int lane = tid & 63;
  const int wv = tid >> 6;
  const int wr = (wv >> 1) * 64, wc = (wv & 1) * 64;
  const int ln = lane & 15, kh = lane >> 4;

  const int srow = tid >> 2;                // 0..63
  const int kch = (tid & 3) << 3;           // 0,8,16,24 (elements)

  f32x4 acc[4][4] = {};

  const int nk = K >> 5;
  const u16* Abase = A + (size_t)(brow + srow) * K + kch;
  const u16* Bbase = Bt + (size_t)(bcol + srow) * K + kch;
  const size_t rstride = (size_t)64 * K;
  u16* lA = sA + srow * 32 + kch;
  u16* lB = sB + srow * 32 + kch;

  for (int kt = 0; kt < nk; ++kt) {
    const int k0 = kt << 5;
    gload_lds16(Abase + k0, lA);
    gload_lds16(Abase + rstride + k0, lA + 64 * 32);
    gload_lds16(Bbase + k0, lB);
    gload_lds16(Bbase + rstride + k0, lB + 64 * 32);
    __syncthreads();
    s16x8 aF[4], bF[4];
#pragma unroll
    for (int m = 0; m < 4; ++m)
      aF[m] = *(const s16x8*)(sA + (wr + m * 16 + ln) * 32 + kh * 8);
#pragma unroll
    for (int n = 0; n < 4; ++n)
      bF[n] = *(const s16x8*)(sB + (wc + n * 16 + ln) * 32 + kh * 8);
#pragma unroll
    for (int m = 0; m < 4; ++m)
#pragma unroll
      for (int n = 0; n < 4; ++n)
        acc[m][n] = __builtin_amdgcn_mfma_f32_16x16x32_bf16(aF[m], bF[n], acc[m][n], 0, 0, 0);
    __syncthreads();
  }

  const int browq = brow + wr;
  const int bcolq = bcol + wc;

  if (MODE == 1) {
    u16* O = (u16*)Cptr;
#pragma unroll
    for (int n = 0; n < 4; ++n) {
      int gcol = bcolq + n * 16 + ln;
      float bv = bias[gcol];
#pragma unroll
      for (int m = 0; m < 4; ++m)
#pragma unroll
        for (int r = 0; r < 4; ++r) {
          int grow = browq + m * 16 + kh * 4 + r;
          float v = fmaxf(acc[m][n][r] + bv, 0.f);
          O[(size_t)grow * N + gcol] = f2bf(v);
        }
    }
  } else {
    float* O = (float*)Cptr;
    float rs[4][4] = {};
#pragma unroll
    for (int n = 0; n < 4; ++n) {
      int gcol = bcolq + n * 16 + ln;
      float bv = bias[gcol];
#pragma unroll
      for (int m = 0; m < 4; ++m)
#pragma unroll
        for (int r = 0; r < 4; ++r) {
          int grow = browq + m * 16 + kh * 4 + r;
          float v = acc[m][n][r] + bv;
          if (MODE == 2) { v = __expf(v); rs[m][r] += v; }
          O[(size_t)grow * N + gcol] = v;
        }
    }
    if (MODE == 2) {
#pragma unroll
      for (int m = 0; m < 4; ++m)
#pragma unroll
        for (int r = 0; r < 4; ++r) {
          float v = rs[m][r];
          v += __shfl_xor(v, 1);
          v += __shfl_xor(v, 2);
          v += __shfl_xor(v, 4);
          v += __shfl_xor(v, 8);
          if (ln == 0) atomicAdd(&rowsum[browq + m * 16 + kh * 4 + r], v);
        }
    }
  }
}

// ---------- persistent LSTM: 64 WGs, Wh stationary in LDS, h staged to LDS ----------
// STEPS: loop count (128 real). SYNC=false: identical compute+publish but zero
// cross-WG waiting (ablation variant; writes only dummy buffers).
template <int STEPS, bool SYNC>
__global__ __launch_bounds__(256)
void lstm_kernel(const float* __restrict__ xg,      // [2048][4096] f32
                 const u16* __restrict__ Wht,       // [4096][1024] bf16 (n-major)
                 const u64* __restrict__ maskb,     // [16][2] bitmask
                 const float* __restrict__ ench, const float* __restrict__ encc,
                 const float* __restrict__ gamma, const float* __restrict__ beta,
                 const float* __restrict__ mmean, const float* __restrict__ mvar,
                 u32* __restrict__ hbuf32,          // [2][16][512] u32
                 u16* __restrict__ hbn,             // [2048][1024] bf16 out
                 u32* __restrict__ cnt) {
  __shared__ u16 sWh[64 * 1024];       // 128KB, XOR-swizzled 16B chunks
  __shared__ char hA[16 * 1024];       // 16KB staged h (half of 16x1024 bf16)
  __shared__ float zx[4][16][16];      // 4KB
  __shared__ u16 sh[16][16];           // 512B

  const int wg = blockIdx.x;
  const int u0 = wg << 4;
  const int tid = threadIdx.x;
  const int lane = tid & 63;
  const int wv = tid >> 6;
  const int ln = lane & 15, kh = lane >> 4;

  // stage Wh slice: local row lr = g*16+ul -> global n = g*1024+u0+ul
#pragma unroll
  for (int it = 0; it < 32; ++it) {
    int idx = it * 256 + tid;          // 0..8191 (64 rows x 128 chunks)
    int lr2 = idx >> 7;
    int ch = idx & 127;
    int g = lr2 >> 4, ul = lr2 & 15;
    const u16* src = Wht + (size_t)(g * 1024 + u0 + ul) * 1024 + ch * 8;
    s16x8 v = *(const s16x8*)src;
    int dstB = lr2 * 2048 + ((ch * 16) ^ ((lr2 & 7) << 4));
    *(s16x8*)((char*)sWh + dstB) = v;
  }

  const int b0 = tid >> 4, ulT = tid & 15, uT = u0 + ulT;
  float cellR = encc[b0 * 1024 + uT];
  float holdR = ench[b0 * 1024 + uT];
  float bn_s = gamma[uT] * rsqrtf(mvar[uT] + 1e-3f);
  float bn_b = beta[uT] - mmean[uT] * bn_s;
  const u64 m0 = maskb[b0 * 2], m1 = maskb[b0 * 2 + 1];

  // publish initial h slice (from ench) into buf0; wave0 only.
  if (wv == 0) {
    int b = lane >> 2, qq = lane & 3;          // 16 batches x 4 u64
    float v0 = ench[b * 1024 + u0 + 4 * qq + 0];
    float v1 = ench[b * 1024 + u0 + 4 * qq + 1];
    float v2 = ench[b * 1024 + u0 + 4 * qq + 2];
    float v3 = ench[b * 1024 + u0 + 4 * qq + 3];
    u32 lo = (u32)f2bf(v0) | ((u32)f2bf(v1) << 16);
    u32 hi = (u32)f2bf(v2) | ((u32)f2bf(v3) << 16);
    AT_ST((u64*)hbuf32 + b * 256 + (u0 >> 2) + qq, (u64)lo | ((u64)hi << 32));
    if (SYNC) {
      asm volatile("s_waitcnt vmcnt(0)" ::: "memory");
      if (lane == 0) {
        (void)__hip_atomic_fetch_add(cnt, 1, __ATOMIC_RELAXED, __HIP_MEMORY_SCOPE_AGENT);
        int c = 0;
        while (AT_LD((const u32*)cnt) < 64u) { if (++c > (1 << 20)) break; }
      }
    }
  }
  __syncthreads();

  // xg(0) prefetch
  const size_t bstride = (size_t)128 * 4096;
  const float* xbase = xg + (size_t)(kh * 4) * bstride + wv * 1024 + u0 + ln;
  float xgr0 = xbase[0];
  float xgr1 = xbase[bstride];
  float xgr2 = xbase[2 * bstride];
  float xgr3 = xbase[3 * bstride];

  const int lr = wv * 16 + ln;
  const int swzrow = lr * 2048;
  const int swzx = (lr & 7) << 4;
  const int sb = tid >> 4;                    // staging row (batch) 0..15
  const int scg = tid & 15;                   // staging 64B group
  const int ardB = ln * 1024;                 // A-read row base
  const int arsw = (ln & 7) << 4;             // A-read swizzle

  for (int s = 0; s < STEPS; ++s) {
    const u64* hsrc = (const u64*)((const char*)hbuf32 + (s & 1) * 32768) +
                      sb * 256 + scg * 8;
    // ---- stage half 0 (cols 0..511) ----
    u64 st0[8];
#pragma unroll
    for (int k = 0; k < 8; ++k) st0[k] = AT_LD(hsrc + k);
    {
      union { u64 q[2]; s16x8 v; } w;
      char* db = hA + sb * 1024;
#pragma unroll
      for (int k = 0; k < 4; ++k) {
        w.q[0] = st0[2 * k]; w.q[1] = st0[2 * k + 1];
        *(s16x8*)(db + ((scg * 64 + k * 16) ^ ((sb & 7) << 4))) = w.v;
      }
    }
    __syncthreads();                           // (a) half0 ready
    // issue half1 loads (latency hidden under MFMA half0)
    u64 st1[8];
#pragma unroll
    for (int k = 0; k < 8; ++k) st1[k] = AT_LD(hsrc + 128 + k);

    f32x4 acc0 = {0.f, 0.f, 0.f, 0.f};
    f32x4 acc1 = {0.f, 0.f, 0.f, 0.f};
#pragma unroll
    for (int kt = 0; kt < 16; kt += 2) {
      s16x8 a0 = *(const s16x8*)(hA + ardB + (((kt * 32 + kh * 8) * 2) ^ arsw));
      s16x8 b0v = *(const s16x8*)((const char*)sWh + swzrow + ((kt * 64 + kh * 16) ^ swzx));
      acc0 = __builtin_amdgcn_mfma_f32_16x16x32_bf16(a0, b0v, acc0, 0, 0, 0);
      s16x8 a1 = *(const s16x8*)(hA + ardB + ((((kt + 1) * 32 + kh * 8) * 2) ^ arsw));
      s16x8 b1v = *(const s16x8*)((const char*)sWh + swzrow + (((kt + 1) * 64 + kh * 16) ^ swzx));
      acc1 = __builtin_amdgcn_mfma_f32_16x16x32_bf16(a1, b1v, acc1, 0, 0, 0);
    }
    __syncthreads();                           // (b) done reading half0
    {
      union { u64 q[2]; s16x8 v; } w;
      char* db = hA + sb * 1024;
#pragma unroll
      for (int k = 0; k < 4; ++k) {
        w.q[0] = st1[2 * k]; w.q[1] = st1[2 * k + 1];
        *(s16x8*)(db + ((scg * 64 + k * 16) ^ ((sb & 7) << 4))) = w.v;
      }
    }
    __syncthreads();                           // (c) half1 ready
#pragma unroll
    for (int kt = 16; kt < 32; kt += 2) {
      s16x8 a0 = *(const s16x8*)(hA + ardB + ((((kt - 16) * 32 + kh * 8) * 2) ^ arsw));
      s16x8 b0v = *(const s16x8*)((const char*)sWh + swzrow + ((kt * 64 + kh * 16) ^ swzx));
      acc0 = __builtin_amdgcn_mfma_f32_16x16x32_bf16(a0, b0v, acc0, 0, 0, 0);
      s16x8 a1 = *(const s16x8*)(hA + ardB + ((((kt - 15) * 32 + kh * 8) * 2) ^ arsw));
      s16x8 b1v = *(const s16x8*)((const char*)sWh + swzrow + (((kt + 1) * 64 + kh * 16) ^ swzx));
      acc1 = __builtin_amdgcn_mfma_f32_16x16x32_bf16(a1, b1v, acc1, 0, 0, 0);
    }
    f32x4 accs = acc0 + acc1;
    zx[wv][kh * 4 + 0][ln] = accs[0] + xgr0;
    zx[wv][kh * 4 + 1][ln] = accs[1] + xgr1;
    zx[wv][kh * 4 + 2][ln] = accs[2] + xgr2;
    zx[wv][kh * 4 + 3][ln] = accs[3] + xgr3;
    __syncthreads();                           // (d) zx ready
    // prefetch next xg (overlaps gates/publish/poll; wave0's vmcnt covers ~gates later)
    if (s < STEPS - 1) {
      const float* xb = xbase + (size_t)(((s + 1) & 127)) * 4096;
      xgr0 = xb[0];
      xgr1 = xb[bstride];
      xgr2 = xb[2 * bstride];
      xgr3 = xb[3 * bstride];
    }
    {
      float zi = zx[0][b0][ulT], zf = zx[1][b0][ulT];
      float zc = zx[2][b0][ulT], zo = zx[3][b0][ulT];
      float ig = 1.f / (1.f + __expf(-zi));
      float fg = 1.f / (1.f + __expf(-zf));
      float og = 1.f / (1.f + __expf(-zo));
      float cc = fmaxf(zc, 0.f);
      float cnew = fg * cellR + ig * cc;
      float hnew = og * fmaxf(cnew, 0.f);
      u64 mm = ((s >> 6) & 1) ? m1 : m0;
      if (!((mm >> (s & 63)) & 1)) { cnew = cellR; hnew = holdR; }
      cellR = cnew;
      holdR = hnew;
      sh[b0][ulT] = f2bf(hnew);
      hbn[(size_t)((b0 * 128 + s) & 2047) * 1024 + uT] = f2bf(hnew * bn_s + bn_b);
    }
    if (s < STEPS - 1) {
      __syncthreads();                         // (e) sh ready
      if (wv == 0) {
        int b = lane >> 2, qq = lane & 3;
        u64 val = *(const u64*)((const char*)sh + b * 32 + qq * 8);
        AT_ST((u64*)((char*)hbuf32 + ((s + 1) & 1) * 32768) + b * 256 + (u0 >> 2) + qq, val);
        if (SYNC) {
          asm volatile("s_waitcnt vmcnt(0)" ::: "memory");
          if (lane == 0) {
            (void)__hip_atomic_fetch_add(cnt, 1, __ATOMIC_RELAXED, __HIP_MEMORY_SCOPE_AGENT);
            const u32 target = (u32)(s + 2) * 64u;
            int c = 0;
            while (AT_LD((const u32*)cnt) < target) { if (++c > (1 << 20)) break; }
          }
        }
      }
      __syncthreads();                         // (f) release
    }
  }
}

// ---------- softmax finish ----------

__global__ void rcp_kernel(float* rs) {
  int i = blockIdx.x * 256 + threadIdx.x;   // 2048 threads
  rs[i] = 1.0f / rs[i];
}

__global__ void scale_kernel(float* __restrict__ out, const float* __restrict__ rinv) {
  const int total4 = 16384000;              // 65,536,000 / 4
  for (int i = blockIdx.x * 256 + threadIdx.x; i < total4; i += gridDim.x * 256) {
    float4* p = (float4*)out + i;
    float4 v = *p;
    int row = i / 8000;                     // 8000 float4 per row
    float sF = rinv[row];
    v.x *= sF; v.y *= sF; v.z *= sF; v.w *= sF;
    *p = v;
  }
}

// ---------- launch ----------

extern "C" void kernel_launch(void* const* d_in, const int* in_sizes, int n_in,
                              void* d_out, int out_size, void* d_ws, size_t ws_size,
                              hipStream_t stream) {
  (void)in_sizes; (void)n_in; (void)out_size;
  const int*   inputs = (const int*)d_in[0];
  const float* ench   = (const float*)d_in[1];
  const float* encc   = (const float*)d_in[2];
  const float* emb    = (const float*)d_in[3];
  const float* Wx     = (const float*)d_in[4];
  const float* Wh     = (const float*)d_in[5];
  const float* bb     = (const float*)d_in[6];
  const float* gamma  = (const float*)d_in[7];
  const float* beta   = (const float*)d_in[8];
  const float* mmean  = (const float*)d_in[9];
  const float* mvar   = (const float*)d_in[10];
  const float* W1     = (const float*)d_in[11];
  const float* b1     = (const float*)d_in[12];
  const float* W2     = (const float*)d_in[13];
  const float* b2     = (const float*)d_in[14];
  float* out = (float*)d_out;

  char* p = (char*)d_ws;
  u32*   cnt    = (u32*)(p + 0);            // word 0
  u32*   cntD   = (u32*)(p + 256);          // ablation counter
  float* rowsum = (float*)(p + 1024);       // 2048 floats; memset covers [0,9216)
  u64*   maskb  = (u64*)(p + 10240);        // 256B, written by mask_kernel
  u32*   hbuf32 = (u32*)(p + 16384);        // 64KB
  u32*   hbufD  = (u32*)(p + 81920);        // 64KB (ablation)
  size_t off = 147456;
  u16*   xbf  = (u16*)(p + off);     off += (size_t)2048 * 512 * 2;     // 2MB
  u16*   Wxt  = (u16*)(p + off);     off += (size_t)4096 * 512 * 2;     // 4MB
  u16*   Wht  = (u16*)(p + off);     off += (size_t)4096 * 1024 * 2;    // 8MB
  u16*   W1t  = (u16*)(p + off);     off += (size_t)1024 * 1024 * 2;    // 2MB
  u16*   W2t  = (u16*)(p + off);     off += (size_t)32000 * 1024 * 2;   // 64MB
  float* xg   = (float*)(p + off);   off += (size_t)2048 * 4096 * 4;    // 32MB
  u16*   hbn  = (u16*)(p + off);     off += (size_t)2048 * 1024 * 2;    // 4MB
  u16*   d1   = (u16*)(p + off);     off += (size_t)2048 * 1024 * 2;    // 4MB
  size_t off_real = off;
  u16*   hbnD = (u16*)(p + off);     off += (size_t)2048 * 1024 * 2;    // 4MB (ablation)
  if (ws_size < off_real) return;  // insufficient scratch; avoid OOB
  const bool do_abl = (ws_size >= off);

  hipMemsetAsync(d_ws, 0, 9216, stream);  // cnt + cntD + rowsum

  embed_kernel<<<512, 256, 0, stream>>>(inputs, emb, xbf);
  mask_kernel<<<1, 64, 0, stream>>>(inputs, maskb);
  transpose_bf16<<<(512 / 32) * (4096 / 32), 256, 0, stream>>>(Wx, Wxt, 512, 4096);
  transpose_bf16<<<(1024 / 32) * (4096 / 32), 256, 0, stream>>>(Wh, Wht, 1024, 4096);
  transpose_bf16<<<(1024 / 32) * (1024 / 32), 256, 0, stream>>>(W1, W1t, 1024, 1024);
  transpose_bf16<<<(1024 / 32) * (32000 / 32), 256, 0, stream>>>(W2, W2t, 1024, 32000);

  gemm_bf16<0><<<16 * 32, 256, 0, stream>>>(xbf, Wxt, bb, xg, nullptr, 2048, 4096, 512);

  lstm_kernel<128, true><<<64, 256, 0, stream>>>(xg, Wht, maskb, ench, encc, gamma, beta,
                                                 mmean, mvar, hbuf32, hbn, cnt);

  gemm_bf16<1><<<16 * 8, 256, 0, stream>>>(hbn, W1t, b1, d1, nullptr, 2048, 1024, 1024);
  gemm_bf16<2><<<16 * 250, 256, 0, stream>>>(d1, W2t, b2, out, rowsum, 2048, 32000, 1024);

  rcp_kernel<<<8, 256, 0, stream>>>(rowsum);
  scale_kernel<<<2048, 256, 0, stream>>>(out, rowsum);

  // ---- diagnostic ablation: identical compute, zero cross-WG waiting ----
  // Writes only dummy buffers; per-step dur_us vs real kernel decomposes
  // sync-latency vs compute cost. Remove once decomposition is known.
  if (do_abl) {
    lstm_kernel<256, false><<<64, 256, 0, stream>>>(xg, Wht, maskb, ench, encc, gamma,
                                                    beta, mmean, mvar, hbufD, hbnD, cntD);
  }
}

// Round 6
// 1048.819 us; speedup vs baseline: 1.9157x; 1.9157x over previous
//
#include <hip/hip_runtime.h>
#include <hip/hip_bf16.h>
#include <stdint.h>

typedef unsigned short u16;
typedef unsigned int u32;
typedef unsigned long long u64;
typedef __attribute__((ext_vector_type(4))) float f32x4;
typedef __attribute__((ext_vector_type(8))) short s16x8;

#define AT_LD(p)    __hip_atomic_load((p), __ATOMIC_RELAXED, __HIP_MEMORY_SCOPE_AGENT)
#define AT_ST(p, v) __hip_atomic_store((p), (v), __ATOMIC_RELAXED, __HIP_MEMORY_SCOPE_AGENT)

// ---------- helpers ----------

static __device__ __forceinline__ u16 f2bf(float f) {
  union { float f; unsigned u; } v; v.f = f;
  unsigned r = v.u + 0x7FFFu + ((v.u >> 16) & 1u);
  return (u16)(r >> 16);
}

static __device__ __forceinline__ void gload_lds16(const void* g, void* l) {
  __builtin_amdgcn_global_load_lds(
      (const __attribute__((address_space(1))) unsigned int*)(uintptr_t)g,
      (__attribute__((address_space(3))) unsigned int*)(uintptr_t)l,
      16, 0, 0);
}

// bank-balancing swizzle for the 32KB h tile in LDS.
// Preserves row (B>>11) and within-16B offset (B&15); XORs the low 3 bits of
// the 16B-position with (row ^ pos>>3) -> ds_read_b128 and ds_write_b64
// patterns both spread across 8 bank-quads (the wave64 floor).
static __device__ __forceinline__ int swzB(int B) {
  int pos = (B >> 4) & 127;
  int row = (B >> 11) & 15;
  int slot = (pos ^ row ^ (pos >> 3)) & 7;
  int npos = (pos & 0x78) | slot;
  return (B & ~0x7F0) | (npos << 4);
}

// ---------- pre-pass kernels ----------

__global__ void embed_kernel(const int* __restrict__ inputs,
                             const float* __restrict__ emb,
                             u16* __restrict__ xbf) {
  int i = blockIdx.x * 256 + threadIdx.x;   // 131072 threads
  int row = i >> 6;
  int e0 = (i & 63) << 3;
  int tok = inputs[row];
  const float* src = emb + (size_t)tok * 512 + e0;
  s16x8 o;
#pragma unroll
  for (int j = 0; j < 8; ++j) o[j] = (short)f2bf(src[j]);
  *(s16x8*)(xbf + (size_t)row * 512 + e0) = o;
}

// bit-pack mask: maskb[b*2+h] bit j = (inputs[b*128 + h*64 + j] != 0)
__global__ void mask_kernel(const int* __restrict__ inputs, u64* __restrict__ mb) {
  int t = threadIdx.x;
  if (t < 32) {
    int b = t >> 1, h = t & 1;
    u64 m = 0;
    for (int j = 0; j < 64; ++j)
      m |= (u64)(inputs[b * 128 + h * 64 + j] != 0) << j;
    mb[t] = m;
  }
}

// Wt[n][k] = bf16(W[k][n]); K,N multiples of 32
__global__ void transpose_bf16(const float* __restrict__ W, u16* __restrict__ Wt,
                               int K, int N) {
  __shared__ float t[32][33];
  int ntn = N >> 5;
  int tn = blockIdx.x % ntn, tk = blockIdx.x / ntn;
  int n0 = tn << 5, k0 = tk << 5;
  int tx = threadIdx.x & 31, ty = threadIdx.x >> 5;  // ty 0..7
#pragma unroll
  for (int j = 0; j < 4; ++j) {
    int k = ty * 4 + j;
    t[k][tx] = W[(size_t)(k0 + k) * N + n0 + tx];
  }
  __syncthreads();
#pragma unroll
  for (int j = 0; j < 4; ++j) {
    int n = ty * 4 + j;
    Wt[(size_t)(n0 + n) * K + k0 + tx] = f2bf(t[tx][n]);
  }
}

// ---------- m97-style bf16 GEMM, 128x128 tile, BK=32 ----------
// MODE 0: C=f32, store acc+bias          (xg)
// MODE 1: C=bf16, store relu(acc+bias)   (d1)
// MODE 2: C=f32, store exp(acc+bias), atomicAdd row sums (logits->exp)
template <int MODE>
__global__ __launch_bounds__(256)
void gemm_bf16(const u16* __restrict__ A, const u16* __restrict__ Bt,
               const float* __restrict__ bias, void* __restrict__ Cptr,
               float* __restrict__ rowsum, int M, int N, int K) {
  (void)M;
  __shared__ u16 sA[128 * 32];
  __shared__ u16 sB[128 * 32];
  const int nbn = N >> 7;
  const int nwg = gridDim.x;
  int bid = blockIdx.x;
  int q = nwg >> 3;                         // grids are multiples of 8
  int swz = (bid & 7) * q + (bid >> 3);     // XCD-aware swizzle (bijective)
  int bm = swz / nbn, bn = swz % nbn;
  const int brow = bm << 7, bcol = bn << 7;

  const int tid = threadIdx.x;
  const int lane = tid & 63;
  const int wv = tid >> 6;
  const int wr = (wv >> 1) * 64, wc = (wv & 1) * 64;
  const int ln = lane & 15, kh = lane >> 4;

  const int srow = tid >> 2;                // 0..63
  const int kch = (tid & 3) << 3;           // 0,8,16,24 (elements)

  f32x4 acc[4][4] = {};

  const int nk = K >> 5;
  const u16* Abase = A + (size_t)(brow + srow) * K + kch;
  const u16* Bbase = Bt + (size_t)(bcol + srow) * K + kch;
  const size_t rstride = (size_t)64 * K;
  u16* lA = sA + srow * 32 + kch;
  u16* lB = sB + srow * 32 + kch;

  for (int kt = 0; kt < nk; ++kt) {
    const int k0 = kt << 5;
    gload_lds16(Abase + k0, lA);
    gload_lds16(Abase + rstride + k0, lA + 64 * 32);
    gload_lds16(Bbase + k0, lB);
    gload_lds16(Bbase + rstride + k0, lB + 64 * 32);
    __syncthreads();
    s16x8 aF[4], bF[4];
#pragma unroll
    for (int m = 0; m < 4; ++m)
      aF[m] = *(const s16x8*)(sA + (wr + m * 16 + ln) * 32 + kh * 8);
#pragma unroll
    for (int n = 0; n < 4; ++n)
      bF[n] = *(const s16x8*)(sB + (wc + n * 16 + ln) * 32 + kh * 8);
#pragma unroll
    for (int m = 0; m < 4; ++m)
#pragma unroll
      for (int n = 0; n < 4; ++n)
        acc[m][n] = __builtin_amdgcn_mfma_f32_16x16x32_bf16(aF[m], bF[n], acc[m][n], 0, 0, 0);
    __syncthreads();
  }

  const int browq = brow + wr;
  const int bcolq = bcol + wc;

  if (MODE == 1) {
    u16* O = (u16*)Cptr;
#pragma unroll
    for (int n = 0; n < 4; ++n) {
      int gcol = bcolq + n * 16 + ln;
      float bv = bias[gcol];
#pragma unroll
      for (int m = 0; m < 4; ++m)
#pragma unroll
        for (int r = 0; r < 4; ++r) {
          int grow = browq + m * 16 + kh * 4 + r;
          float v = fmaxf(acc[m][n][r] + bv, 0.f);
          O[(size_t)grow * N + gcol] = f2bf(v);
        }
    }
  } else {
    float* O = (float*)Cptr;
    float rs[4][4] = {};
#pragma unroll
    for (int n = 0; n < 4; ++n) {
      int gcol = bcolq + n * 16 + ln;
      float bv = bias[gcol];
#pragma unroll
      for (int m = 0; m < 4; ++m)
#pragma unroll
        for (int r = 0; r < 4; ++r) {
          int grow = browq + m * 16 + kh * 4 + r;
          float v = acc[m][n][r] + bv;
          if (MODE == 2) { v = __expf(v); rs[m][r] += v; }
          O[(size_t)grow * N + gcol] = v;
        }
    }
    if (MODE == 2) {
#pragma unroll
      for (int m = 0; m < 4; ++m)
#pragma unroll
        for (int r = 0; r < 4; ++r) {
          float v = rs[m][r];
          v += __shfl_xor(v, 1);
          v += __shfl_xor(v, 2);
          v += __shfl_xor(v, 4);
          v += __shfl_xor(v, 8);
          if (ln == 0) atomicAdd(&rowsum[browq + m * 16 + kh * 4 + r], v);
        }
    }
  }
}

// ---------- persistent LSTM: 64 WGs, Wh in VGPRs, gates in-wave ----------
// Wave wv's 16 MFMA columns map to local col ln = (gate g = ln&3, unit
// u0 + wv*4 + (ln>>2)). Gate combine = 3 shfl_xor within lane quads.
// h exchange via relaxed agent-scope atomics on a parity-2 global buffer
// (linear [16][1024] bf16); LDS copy is swzB-swizzled for bank balance.
__global__ __launch_bounds__(256, 1)
void lstm_kernel(const float* __restrict__ xg,      // [2048][4096] f32
                 const u16* __restrict__ Wht,       // [4096][1024] bf16 (n-major)
                 const u64* __restrict__ maskb,     // [16][2] bitmask
                 const float* __restrict__ ench, const float* __restrict__ encc,
                 const float* __restrict__ gamma, const float* __restrict__ beta,
                 const float* __restrict__ mmean, const float* __restrict__ mvar,
                 u32* __restrict__ hbuf32,          // [2][16][512] u32 (linear)
                 u16* __restrict__ hbn,             // [2048][1024] bf16 out
                 u32* __restrict__ cnt) {
  __shared__ char hA[32 * 1024];       // staged h(s), swizzled

  const int wg = blockIdx.x;
  const int u0 = wg << 4;
  const int tid = threadIdx.x;
  const int lane = tid & 63;
  const int wv = tid >> 6;
  const int ln = lane & 15, kh = lane >> 4;

  const int g = ln & 3;                // gate index (i,f,cc,o)
  const int ul = ln >> 2;              // unit within wave block
  const int unit = u0 + wv * 4 + ul;

  // ---- Wh preload into 128 VGPRs (one-time) ----
  s16x8 bW[32];
  {
    const u16* wrow = Wht + (size_t)(g * 1024 + unit) * 1024 + kh * 8;
#pragma unroll
    for (int kt = 0; kt < 32; ++kt)
      bW[kt] = *(const s16x8*)(wrow + kt * 32);
  }

  // per-lane state for 4 batches (kh*4+r); only g==0 lanes meaningful
  float cellR[4], holdR[4];
  u64 mA[4], mB[4];
  const float bn_s = gamma[unit] * rsqrtf(mvar[unit] + 1e-3f);
  const float bn_b = beta[unit] - mmean[unit] * bn_s;
#pragma unroll
  for (int r = 0; r < 4; ++r) {
    int batch = kh * 4 + r;
    cellR[r] = encc[batch * 1024 + unit];
    holdR[r] = ench[batch * 1024 + unit];
    mA[r] = maskb[batch * 2];
    mB[r] = maskb[batch * 2 + 1];
  }

  // ---- initial publish of h(0) (bf16 of ench) into parity-0 buffer ----
#pragma unroll
  for (int r = 0; r < 4; ++r) {
    u32 w = (u32)f2bf(holdR[r]);
    u32 pw = (u32)__shfl_xor((int)w, 4);   // partner unit+1 (same gate)
    if ((ln & 7) == 0) {
      int batch = kh * 4 + r;
      int B = batch * 2048 + unit * 2;
      AT_ST((u32*)((char*)hbuf32 + B), (w & 0xFFFFu) | (pw << 16));
    }
  }
  asm volatile("s_waitcnt vmcnt(0)" ::: "memory");
  __syncthreads();
  if (tid == 0) {
    (void)__hip_atomic_fetch_add(cnt, 1, __ATOMIC_RELAXED, __HIP_MEMORY_SCOPE_AGENT);
    int c = 0;
    while (AT_LD((const u32*)cnt) < 64u) { if (++c > (1 << 20)) break; }
  }
  __syncthreads();

  // xg(0) prefetch: col = g*1024 + unit, rows = batches kh*4+r
  const size_t bstride = (size_t)128 * 4096;
  const float* xbase = xg + (size_t)(kh * 4) * bstride + g * 1024 + unit;
  float xgr[4];
#pragma unroll
  for (int r = 0; r < 4; ++r) xgr[r] = xbase[r * bstride];

  for (int s = 0; s < 128; ++s) {
    // ---- stage h(s): 16 coalesced u64 uncached loads -> swizzled LDS ----
    const u64* src = (const u64*)((const char*)hbuf32 + (s & 1) * 32768) + tid;
    u64 st[16];
#pragma unroll
    for (int k = 0; k < 16; ++k) st[k] = AT_LD(src + k * 256);
#pragma unroll
    for (int k = 0; k < 16; ++k)
      *(u64*)(hA + swzB(k * 2048 + tid * 8)) = st[k];
    __syncthreads();                           // (A) hA ready

    // ---- 32 MFMA, 2 chains; A from LDS, B from VGPRs ----
    f32x4 acc0 = {0.f, 0.f, 0.f, 0.f};
    f32x4 acc1 = {0.f, 0.f, 0.f, 0.f};
#pragma unroll
    for (int kt = 0; kt < 32; kt += 2) {
      s16x8 a0 = *(const s16x8*)(hA + swzB(ln * 2048 + kt * 64 + kh * 16));
      acc0 = __builtin_amdgcn_mfma_f32_16x16x32_bf16(a0, bW[kt], acc0, 0, 0, 0);
      s16x8 a1 = *(const s16x8*)(hA + swzB(ln * 2048 + (kt + 1) * 64 + kh * 16));
      acc1 = __builtin_amdgcn_mfma_f32_16x16x32_bf16(a1, bW[kt + 1], acc1, 0, 0, 0);
    }

    // ---- gates fully in-wave (lane quads 4u..4u+3 hold i,f,cc,o) ----
    u16 hbb[4], hbnb[4];
#pragma unroll
    for (int r = 0; r < 4; ++r) {
      float z = acc0[r] + acc1[r] + xgr[r];
      float sig = 1.f / (1.f + __expf(-z));
      float val = (g == 2) ? fmaxf(z, 0.f) : sig;
      float v1 = __shfl_xor(val, 1);
      float v2 = __shfl_xor(val, 2);
      float v3 = __shfl_xor(val, 3);
      // g==0 view: val=i, v1=f, v2=cc, v3=o
      float cnew = v1 * cellR[r] + val * v2;
      float hnew = v3 * fmaxf(cnew, 0.f);
      u64 mm = (s < 64) ? mA[r] : mB[r];
      if (!((mm >> (s & 63)) & 1)) { cnew = cellR[r]; hnew = holdR[r]; }
      cellR[r] = cnew;
      holdR[r] = hnew;
      hbb[r] = f2bf(hnew);
      hbnb[r] = f2bf(hnew * bn_s + bn_b);
    }

    // ---- publish h(s+1) + hbn(s) (pair-packed u32, lanes ln in {0,8}) ----
#pragma unroll
    for (int r = 0; r < 4; ++r) {
      u32 w = (u32)hbb[r] | ((u32)hbnb[r] << 16);
      u32 pw = (u32)__shfl_xor((int)w, 4);
      if ((ln & 7) == 0) {
        int batch = kh * 4 + r;
        u32 hpair = (w & 0xFFFFu) | ((pw & 0xFFFFu) << 16);
        u32 bnpair = (w >> 16) | (pw & 0xFFFF0000u);
        if (s < 127) {
          int B = batch * 2048 + unit * 2;
          AT_ST((u32*)((char*)hbuf32 + ((s + 1) & 1) * 32768 + B), hpair);
        }
        *(u32*)((char*)hbn + (size_t)(batch * 128 + s) * 2048 + unit * 2) = bnpair;
      }
    }

    if (s < 127) {
      asm volatile("s_waitcnt vmcnt(0)" ::: "memory");
      __syncthreads();                         // (B) all publishes complete
      if (tid == 0)
        (void)__hip_atomic_fetch_add(cnt, 1, __ATOMIC_RELAXED, __HIP_MEMORY_SCOPE_AGENT);
      // xg(s+1) prefetch overlaps the poll
      {
        const float* xb = xbase + (size_t)(s + 1) * 4096;
#pragma unroll
        for (int r = 0; r < 4; ++r) xgr[r] = xb[r * bstride];
      }
      if (tid == 0) {
        const u32 target = (u32)(s + 2) * 64u;
        int c = 0;
        while (AT_LD((const u32*)cnt) < target) { if (++c > (1 << 20)) break; }
      }
      __syncthreads();                         // (C) release
    }
  }
}

// ---------- softmax finish ----------

__global__ void rcp_kernel(float* rs) {
  int i = blockIdx.x * 256 + threadIdx.x;   // 2048 threads
  rs[i] = 1.0f / rs[i];
}

__global__ void scale_kernel(float* __restrict__ out, const float* __restrict__ rinv) {
  const int total4 = 16384000;              // 65,536,000 / 4
  for (int i = blockIdx.x * 256 + threadIdx.x; i < total4; i += gridDim.x * 256) {
    float4* p = (float4*)out + i;
    float4 v = *p;
    int row = i / 8000;                     // 8000 float4 per row
    float sF = rinv[row];
    v.x *= sF; v.y *= sF; v.z *= sF; v.w *= sF;
    *p = v;
  }
}

// ---------- launch ----------

extern "C" void kernel_launch(void* const* d_in, const int* in_sizes, int n_in,
                              void* d_out, int out_size, void* d_ws, size_t ws_size,
                              hipStream_t stream) {
  (void)in_sizes; (void)n_in; (void)out_size;
  const int*   inputs = (const int*)d_in[0];
  const float* ench   = (const float*)d_in[1];
  const float* encc   = (const float*)d_in[2];
  const float* emb    = (const float*)d_in[3];
  const float* Wx     = (const float*)d_in[4];
  const float* Wh     = (const float*)d_in[5];
  const float* bb     = (const float*)d_in[6];
  const float* gamma  = (const float*)d_in[7];
  const float* beta   = (const float*)d_in[8];
  const float* mmean  = (const float*)d_in[9];
  const float* mvar   = (const float*)d_in[10];
  const float* W1     = (const float*)d_in[11];
  const float* b1     = (const float*)d_in[12];
  const float* W2     = (const float*)d_in[13];
  const float* b2     = (const float*)d_in[14];
  float* out = (float*)d_out;

  char* p = (char*)d_ws;
  u32*   cnt    = (u32*)(p + 0);            // word 0
  float* rowsum = (float*)(p + 1024);       // 2048 floats; memset covers [0,9216)
  u64*   maskb  = (u64*)(p + 10240);        // 256B, written by mask_kernel
  u32*   hbuf32 = (u32*)(p + 16384);        // 64KB (2 x 32KB parity tiles)
  size_t off = 81920;
  u16*   xbf  = (u16*)(p + off);     off += (size_t)2048 * 512 * 2;     // 2MB
  u16*   Wxt  = (u16*)(p + off);     off += (size_t)4096 * 512 * 2;     // 4MB
  u16*   Wht  = (u16*)(p + off);     off += (size_t)4096 * 1024 * 2;    // 8MB
  u16*   W1t  = (u16*)(p + off);     off += (size_t)1024 * 1024 * 2;    // 2MB
  u16*   W2t  = (u16*)(p + off);     off += (size_t)32000 * 1024 * 2;   // 64MB
  float* xg   = (float*)(p + off);   off += (size_t)2048 * 4096 * 4;    // 32MB
  u16*   hbn  = (u16*)(p + off);     off += (size_t)2048 * 1024 * 2;    // 4MB
  u16*   d1   = (u16*)(p + off);     off += (size_t)2048 * 1024 * 2;    // 4MB
  if (ws_size < off) return;  // insufficient scratch; avoid OOB

  hipMemsetAsync(d_ws, 0, 9216, stream);  // cnt + rowsum

  embed_kernel<<<512, 256, 0, stream>>>(inputs, emb, xbf);
  mask_kernel<<<1, 64, 0, stream>>>(inputs, maskb);
  transpose_bf16<<<(512 / 32) * (4096 / 32), 256, 0, stream>>>(Wx, Wxt, 512, 4096);
  transpose_bf16<<<(1024 / 32) * (4096 / 32), 256, 0, stream>>>(Wh, Wht, 1024, 4096);
  transpose_bf16<<<(1024 / 32) * (1024 / 32), 256, 0, stream>>>(W1, W1t, 1024, 1024);
  transpose_bf16<<<(1024 / 32) * (32000 / 32), 256, 0, stream>>>(W2, W2t, 1024, 32000);

  gemm_bf16<0><<<16 * 32, 256, 0, stream>>>(xbf, Wxt, bb, xg, nullptr, 2048, 4096, 512);

  lstm_kernel<<<64, 256, 0, stream>>>(xg, Wht, maskb, ench, encc, gamma, beta,
                                      mmean, mvar, hbuf32, hbn, cnt);

  gemm_bf16<1><<<16 * 8, 256, 0, stream>>>(hbn, W1t, b1, d1, nullptr, 2048, 1024, 1024);
  gemm_bf16<2><<<16 * 250, 256, 0, stream>>>(d1, W2t, b2, out, rowsum, 2048, 32000, 1024);

  rcp_kernel<<<8, 256, 0, stream>>>(rowsum);
  scale_kernel<<<2048, 256, 0, stream>>>(out, rowsum);
}

// Round 7
// 1002.662 us; speedup vs baseline: 2.0039x; 1.0460x over previous
//
#include <hip/hip_runtime.h>
#include <hip/hip_bf16.h>
#include <stdint.h>

typedef unsigned short u16;
typedef unsigned int u32;
typedef unsigned long long u64;
typedef __attribute__((ext_vector_type(4))) float f32x4;
typedef __attribute__((ext_vector_type(8))) short s16x8;

#define AT_LD(p)    __hip_atomic_load((p), __ATOMIC_RELAXED, __HIP_MEMORY_SCOPE_AGENT)
#define AT_ST(p, v) __hip_atomic_store((p), (v), __ATOMIC_RELAXED, __HIP_MEMORY_SCOPE_AGENT)

// ---------- helpers ----------

static __device__ __forceinline__ u16 f2bf(float f) {
  union { float f; unsigned u; } v; v.f = f;
  unsigned r = v.u + 0x7FFFu + ((v.u >> 16) & 1u);
  return (u16)(r >> 16);
}

static __device__ __forceinline__ void gload_lds16(const void* g, void* l) {
  __builtin_amdgcn_global_load_lds(
      (const __attribute__((address_space(1))) unsigned int*)(uintptr_t)g,
      (__attribute__((address_space(3))) unsigned int*)(uintptr_t)l,
      16, 0, 0);
}

// bank-balancing swizzle for the 32KB h tile in LDS (see r6).
static __device__ __forceinline__ int swzB(int B) {
  int pos = (B >> 4) & 127;
  int row = (B >> 11) & 15;
  int slot = (pos ^ row ^ (pos >> 3)) & 7;
  int npos = (pos & 0x78) | slot;
  return (B & ~0x7F0) | (npos << 4);
}

// ---------- pre-pass kernels ----------

__global__ void embed_kernel(const int* __restrict__ inputs,
                             const float* __restrict__ emb,
                             u16* __restrict__ xbf) {
  int i = blockIdx.x * 256 + threadIdx.x;   // 131072 threads
  int row = i >> 6;
  int e0 = (i & 63) << 3;
  int tok = inputs[row];
  const float* src = emb + (size_t)tok * 512 + e0;
  s16x8 o;
#pragma unroll
  for (int j = 0; j < 8; ++j) o[j] = (short)f2bf(src[j]);
  *(s16x8*)(xbf + (size_t)row * 512 + e0) = o;
}

// bit-pack mask: maskb[b*2+h] bit j = (inputs[b*128 + h*64 + j] != 0)
__global__ void mask_kernel(const int* __restrict__ inputs, u64* __restrict__ mb) {
  int t = threadIdx.x;
  if (t < 32) {
    int b = t >> 1, h = t & 1;
    u64 m = 0;
    for (int j = 0; j < 64; ++j)
      m |= (u64)(inputs[b * 128 + h * 64 + j] != 0) << j;
    mb[t] = m;
  }
}

// Wt[n][k] = bf16(W[k][n]); K,N multiples of 32
__global__ void transpose_bf16(const float* __restrict__ W, u16* __restrict__ Wt,
                               int K, int N) {
  __shared__ float t[32][33];
  int ntn = N >> 5;
  int tn = blockIdx.x % ntn, tk = blockIdx.x / ntn;
  int n0 = tn << 5, k0 = tk << 5;
  int tx = threadIdx.x & 31, ty = threadIdx.x >> 5;  // ty 0..7
#pragma unroll
  for (int j = 0; j < 4; ++j) {
    int k = ty * 4 + j;
    t[k][tx] = W[(size_t)(k0 + k) * N + n0 + tx];
  }
  __syncthreads();
#pragma unroll
  for (int j = 0; j < 4; ++j) {
    int n = ty * 4 + j;
    Wt[(size_t)(n0 + n) * K + k0 + tx] = f2bf(t[tx][n]);
  }
}

// ---------- m97-style bf16 GEMM, 128x128 tile, BK=32 ----------
// MODE 0: C=f32, store acc+bias          (xg)
// MODE 1: C=bf16, store relu(acc+bias)   (d1)
// MODE 2: C=f32, store exp(acc+bias), atomicAdd row sums (logits->exp)
template <int MODE>
__global__ __launch_bounds__(256)
void gemm_bf16(const u16* __restrict__ A, const u16* __restrict__ Bt,
               const float* __restrict__ bias, void* __restrict__ Cptr,
               float* __restrict__ rowsum, int M, int N, int K) {
  (void)M;
  __shared__ u16 sA[128 * 32];
  __shared__ u16 sB[128 * 32];
  const int nbn = N >> 7;
  const int nwg = gridDim.x;
  int bid = blockIdx.x;
  int q = nwg >> 3;                         // grids are multiples of 8
  int swz = (bid & 7) * q + (bid >> 3);     // XCD-aware swizzle (bijective)
  int bm = swz / nbn, bn = swz % nbn;
  const int brow = bm << 7, bcol = bn << 7;

  const int tid = threadIdx.x;
  const int lane = tid & 63;
  const int wv = tid >> 6;
  const int wr = (wv >> 1) * 64, wc = (wv & 1) * 64;
  const int ln = lane & 15, kh = lane >> 4;

  const int srow = tid >> 2;                // 0..63
  const int kch = (tid & 3) << 3;           // 0,8,16,24 (elements)

  f32x4 acc[4][4] = {};

  const int nk = K >> 5;
  const u16* Abase = A + (size_t)(brow + srow) * K + kch;
  const u16* Bbase = Bt + (size_t)(bcol + srow) * K + kch;
  const size_t rstride = (size_t)64 * K;
  u16* lA = sA + srow * 32 + kch;
  u16* lB = sB + srow * 32 + kch;

  for (int kt = 0; kt < nk; ++kt) {
    const int k0 = kt << 5;
    gload_lds16(Abase + k0, lA);
    gload_lds16(Abase + rstride + k0, lA + 64 * 32);
    gload_lds16(Bbase + k0, lB);
    gload_lds16(Bbase + rstride + k0, lB + 64 * 32);
    __syncthreads();
    s16x8 aF[4], bF[4];
#pragma unroll
    for (int m = 0; m < 4; ++m)
      aF[m] = *(const s16x8*)(sA + (wr + m * 16 + ln) * 32 + kh * 8);
#pragma unroll
    for (int n = 0; n < 4; ++n)
      bF[n] = *(const s16x8*)(sB + (wc + n * 16 + ln) * 32 + kh * 8);
#pragma unroll
    for (int m = 0; m < 4; ++m)
#pragma unroll
      for (int n = 0; n < 4; ++n)
        acc[m][n] = __builtin_amdgcn_mfma_f32_16x16x32_bf16(aF[m], bF[n], acc[m][n], 0, 0, 0);
    __syncthreads();
  }

  const int browq = brow + wr;
  const int bcolq = bcol + wc;

  if (MODE == 1) {
    u16* O = (u16*)Cptr;
#pragma unroll
    for (int n = 0; n < 4; ++n) {
      int gcol = bcolq + n * 16 + ln;
      float bv = bias[gcol];
#pragma unroll
      for (int m = 0; m < 4; ++m)
#pragma unroll
        for (int r = 0; r < 4; ++r) {
          int grow = browq + m * 16 + kh * 4 + r;
          float v = fmaxf(acc[m][n][r] + bv, 0.f);
          O[(size_t)grow * N + gcol] = f2bf(v);
        }
    }
  } else {
    float* O = (float*)Cptr;
    float rs[4][4] = {};
#pragma unroll
    for (int n = 0; n < 4; ++n) {
      int gcol = bcolq + n * 16 + ln;
      float bv = bias[gcol];
#pragma unroll
      for (int m = 0; m < 4; ++m)
#pragma unroll
        for (int r = 0; r < 4; ++r) {
          int grow = browq + m * 16 + kh * 4 + r;
          float v = acc[m][n][r] + bv;
          if (MODE == 2) { v = __expf(v); rs[m][r] += v; }
          O[(size_t)grow * N + gcol] = v;
        }
    }
    if (MODE == 2) {
#pragma unroll
      for (int m = 0; m < 4; ++m)
#pragma unroll
        for (int r = 0; r < 4; ++r) {
          float v = rs[m][r];
          v += __shfl_xor(v, 1);
          v += __shfl_xor(v, 2);
          v += __shfl_xor(v, 4);
          v += __shfl_xor(v, 8);
          if (ln == 0) atomicAdd(&rowsum[browq + m * 16 + kh * 4 + r], v);
        }
    }
  }
}

// ---------- persistent LSTM: 64 WGs x 512 threads, k-split, Wh in VGPRs ----------
// 8 waves: wave wv = (col-group cg = wv&3, k-half kh2 = wv>>2).
// Within wave: col ln -> (gate g = ln&3, unit = u0 + cg*4 + (ln>>2)).
// Each wave: 16 MFMA over its 512-k slice; partials combined via 4KB LDS.
// Stage: 8 explicit back-to-back sc0sc1 loads/thread (one exposed fabric RT).
__global__ __launch_bounds__(512, 1)
void lstm_kernel(const float* __restrict__ xg,      // [2048][4096] f32
                 const u16* __restrict__ Wht,       // [4096][1024] bf16 (n-major)
                 const u64* __restrict__ maskb,     // [16][2] bitmask
                 const float* __restrict__ ench, const float* __restrict__ encc,
                 const float* __restrict__ gamma, const float* __restrict__ beta,
                 const float* __restrict__ mmean, const float* __restrict__ mvar,
                 u32* __restrict__ hbuf32,          // [2][16][512] u32 (linear)
                 u16* __restrict__ hbn,             // [2048][1024] bf16 out
                 u32* __restrict__ cnt) {
  __shared__ char hA[32 * 1024];       // staged h(s), swizzled
  __shared__ float zxP[8][16][16];     // per-wave partial z

  const int wg = blockIdx.x;
  const int u0 = wg << 4;
  const int tid = threadIdx.x;
  const int lane = tid & 63;
  const int wv = tid >> 6;
  const int ln = lane & 15, khq = lane >> 4;
  const int cg = wv & 3, kh2 = wv >> 2;

  const int g = ln & 3;                // gate index (i,f,cc,o)
  const int unit = u0 + cg * 4 + (ln >> 2);

  // ---- Wh preload: 16 x s16x8 = 64 VGPRs, pinned live ----
  s16x8 bW[16];
  {
    const u16* wrow = Wht + (size_t)(g * 1024 + unit) * 1024 + kh2 * 512 + khq * 8;
#pragma unroll
    for (int kt = 0; kt < 16; ++kt)
      bW[kt] = *(const s16x8*)(wrow + kt * 32);
#pragma unroll
    for (int kt = 0; kt < 16; ++kt)
      asm volatile("" : "+v"(bW[kt]));
  }

  // per-lane state (meaningful in waves 0-3 only)
  float cellR[4] = {}, holdR[4] = {}, xgr[4] = {};
  u64 mA[4] = {}, mB[4] = {};
  float bn_s = 0.f, bn_b = 0.f;
  const size_t bstride = (size_t)128 * 4096;
  const float* xbase = xg + (size_t)(khq * 4) * bstride + g * 1024 + unit;
  if (kh2 == 0) {
    bn_s = gamma[unit] * rsqrtf(mvar[unit] + 1e-3f);
    bn_b = beta[unit] - mmean[unit] * bn_s;
#pragma unroll
    for (int r = 0; r < 4; ++r) {
      int batch = khq * 4 + r;
      cellR[r] = encc[batch * 1024 + unit];
      holdR[r] = ench[batch * 1024 + unit];
      mA[r] = maskb[batch * 2];
      mB[r] = maskb[batch * 2 + 1];
    }
    // initial publish of h(0) into parity-0 buffer
#pragma unroll
    for (int r = 0; r < 4; ++r) {
      u32 w = (u32)f2bf(holdR[r]);
      u32 pw = (u32)__shfl_xor((int)w, 4);
      if ((ln & 7) == 0) {
        int batch = khq * 4 + r;
        AT_ST((u32*)((char*)hbuf32 + batch * 2048 + unit * 2), (w & 0xFFFFu) | (pw << 16));
      }
    }
#pragma unroll
    for (int r = 0; r < 4; ++r) xgr[r] = xbase[r * bstride];   // xg(0) prefetch
  }
  asm volatile("s_waitcnt vmcnt(0)" ::: "memory");
  __syncthreads();
  if (tid == 0) {
    int oldv = (int)__hip_atomic_fetch_add(cnt, 1, __ATOMIC_RELAXED, __HIP_MEMORY_SCOPE_AGENT);
    if (oldv != 63) {
      int c = 0;
      while (AT_LD((const u32*)cnt) < 64u) { if (++c > (1 << 20)) break; }
    }
  }
  __syncthreads();

  for (int s = 0; s < 128; ++s) {
    // ---- stage h(s): 8 back-to-back uncached loads, one waitcnt ----
    u64 st[8];
    {
      const u64* base = (const u64*)((const char*)hbuf32 + (s & 1) * 32768) + tid;
#pragma unroll
      for (int k = 0; k < 8; ++k) {
        const u64* pp = base + k * 512;
        asm volatile("global_load_dwordx2 %0, %1, off sc0 sc1" : "=v"(st[k]) : "v"(pp));
      }
      asm volatile("s_waitcnt vmcnt(0)" ::: "memory");
      __builtin_amdgcn_sched_barrier(0);
#pragma unroll
      for (int k = 0; k < 8; ++k)
        *(u64*)(hA + swzB((tid + k * 512) * 8)) = st[k];
    }
    __syncthreads();                           // (A) hA ready

    // ---- 16 MFMA over this wave's 512-k slice, 2 chains ----
    f32x4 acc0 = {0.f, 0.f, 0.f, 0.f};
    f32x4 acc1 = {0.f, 0.f, 0.f, 0.f};
#pragma unroll
    for (int kt = 0; kt < 16; kt += 2) {
      s16x8 a0 = *(const s16x8*)(hA + swzB(ln * 2048 + kh2 * 1024 + kt * 64 + khq * 16));
      acc0 = __builtin_amdgcn_mfma_f32_16x16x32_bf16(a0, bW[kt], acc0, 0, 0, 0);
      s16x8 a1 = *(const s16x8*)(hA + swzB(ln * 2048 + kh2 * 1024 + (kt + 1) * 64 + khq * 16));
      acc1 = __builtin_amdgcn_mfma_f32_16x16x32_bf16(a1, bW[kt + 1], acc1, 0, 0, 0);
    }
    f32x4 accs = acc0 + acc1;
#pragma unroll
    for (int r = 0; r < 4; ++r) zxP[wv][khq * 4 + r][ln] = accs[r];
    __syncthreads();                           // (B2) partials ready

    if (kh2 == 0) {
      // ---- combine k-halves + gates (in-wave) + publish ----
      u16 hbb[4], hbnb[4];
#pragma unroll
      for (int r = 0; r < 4; ++r) {
        int batch = khq * 4 + r;
        float z = zxP[cg][batch][ln] + zxP[cg + 4][batch][ln] + xgr[r];
        float sig = 1.f / (1.f + __expf(-z));
        float val = (g == 2) ? fmaxf(z, 0.f) : sig;
        float v1 = __shfl_xor(val, 1);
        float v2 = __shfl_xor(val, 2);
        float v3 = __shfl_xor(val, 3);
        float cnew = v1 * cellR[r] + val * v2;   // f*c + i*cc (g==0 view)
        float hnew = v3 * fmaxf(cnew, 0.f);
        u64 mm = (s < 64) ? mA[r] : mB[r];
        if (!((mm >> (s & 63)) & 1)) { cnew = cellR[r]; hnew = holdR[r]; }
        cellR[r] = cnew;
        holdR[r] = hnew;
        hbb[r] = f2bf(hnew);
        hbnb[r] = f2bf(hnew * bn_s + bn_b);
      }
#pragma unroll
      for (int r = 0; r < 4; ++r) {
        u32 w = (u32)hbb[r] | ((u32)hbnb[r] << 16);
        u32 pw = (u32)__shfl_xor((int)w, 4);
        if ((ln & 7) == 0) {
          int batch = khq * 4 + r;
          u32 hpair = (w & 0xFFFFu) | ((pw & 0xFFFFu) << 16);
          u32 bnpair = (w >> 16) | (pw & 0xFFFF0000u);
          if (s < 127) {
            int B = batch * 2048 + unit * 2;
            AT_ST((u32*)((char*)hbuf32 + ((s + 1) & 1) * 32768 + B), hpair);
          }
          *(u32*)((char*)hbn + (size_t)(batch * 128 + s) * 2048 + unit * 2) = bnpair;
        }
      }
    }

    if (s < 127) {
      asm volatile("s_waitcnt vmcnt(0)" ::: "memory");
      __syncthreads();                         // (B3) all publishes drained
      int oldv = -1;
      if (tid == 0)
        oldv = (int)__hip_atomic_fetch_add(cnt, 1, __ATOMIC_RELAXED, __HIP_MEMORY_SCOPE_AGENT);
      if (kh2 == 0) {                          // xg(s+1) prefetch overlaps poll
        const float* xb = xbase + (size_t)(s + 1) * 4096;
#pragma unroll
        for (int r = 0; r < 4; ++r) xgr[r] = xb[r * bstride];
      }
      if (tid == 0) {
        const u32 target = (u32)(s + 2) * 64u;
        if (oldv != (int)target - 1) {
          int c = 0;
          while (AT_LD((const u32*)cnt) < target) { if (++c > (1 << 20)) break; }
        }
      }
      __syncthreads();                         // (C) release
    }
  }
}

// ---------- softmax finish ----------

__global__ void rcp_kernel(float* rs) {
  int i = blockIdx.x * 256 + threadIdx.x;   // 2048 threads
  rs[i] = 1.0f / rs[i];
}

__global__ void scale_kernel(float* __restrict__ out, const float* __restrict__ rinv) {
  const int total4 = 16384000;              // 65,536,000 / 4
  for (int i = blockIdx.x * 256 + threadIdx.x; i < total4; i += gridDim.x * 256) {
    float4* p = (float4*)out + i;
    float4 v = *p;
    int row = i / 8000;                     // 8000 float4 per row
    float sF = rinv[row];
    v.x *= sF; v.y *= sF; v.z *= sF; v.w *= sF;
    *p = v;
  }
}

// ---------- launch ----------

extern "C" void kernel_launch(void* const* d_in, const int* in_sizes, int n_in,
                              void* d_out, int out_size, void* d_ws, size_t ws_size,
                              hipStream_t stream) {
  (void)in_sizes; (void)n_in; (void)out_size;
  const int*   inputs = (const int*)d_in[0];
  const float* ench   = (const float*)d_in[1];
  const float* encc   = (const float*)d_in[2];
  const float* emb    = (const float*)d_in[3];
  const float* Wx     = (const float*)d_in[4];
  const float* Wh     = (const float*)d_in[5];
  const float* bb     = (const float*)d_in[6];
  const float* gamma  = (const float*)d_in[7];
  const float* beta   = (const float*)d_in[8];
  const float* mmean  = (const float*)d_in[9];
  const float* mvar   = (const float*)d_in[10];
  const float* W1     = (const float*)d_in[11];
  const float* b1     = (const float*)d_in[12];
  const float* W2     = (const float*)d_in[13];
  const float* b2     = (const float*)d_in[14];
  float* out = (float*)d_out;

  char* p = (char*)d_ws;
  u32*   cnt    = (u32*)(p + 0);            // word 0
  float* rowsum = (float*)(p + 1024);       // 2048 floats; memset covers [0,9216)
  u64*   maskb  = (u64*)(p + 10240);        // 256B, written by mask_kernel
  u32*   hbuf32 = (u32*)(p + 16384);        // 64KB (2 x 32KB parity tiles)
  size_t off = 81920;
  u16*   xbf  = (u16*)(p + off);     off += (size_t)2048 * 512 * 2;     // 2MB
  u16*   Wxt  = (u16*)(p + off);     off += (size_t)4096 * 512 * 2;     // 4MB
  u16*   Wht  = (u16*)(p + off);     off += (size_t)4096 * 1024 * 2;    // 8MB
  u16*   W1t  = (u16*)(p + off);     off += (size_t)1024 * 1024 * 2;    // 2MB
  u16*   W2t  = (u16*)(p + off);     off += (size_t)32000 * 1024 * 2;   // 64MB
  float* xg   = (float*)(p + off);   off += (size_t)2048 * 4096 * 4;    // 32MB
  u16*   hbn  = (u16*)(p + off);     off += (size_t)2048 * 1024 * 2;    // 4MB
  u16*   d1   = (u16*)(p + off);     off += (size_t)2048 * 1024 * 2;    // 4MB
  if (ws_size < off) return;  // insufficient scratch; avoid OOB

  hipMemsetAsync(d_ws, 0, 9216, stream);  // cnt + rowsum

  embed_kernel<<<512, 256, 0, stream>>>(inputs, emb, xbf);
  mask_kernel<<<1, 64, 0, stream>>>(inputs, maskb);
  transpose_bf16<<<(512 / 32) * (4096 / 32), 256, 0, stream>>>(Wx, Wxt, 512, 4096);
  transpose_bf16<<<(1024 / 32) * (4096 / 32), 256, 0, stream>>>(Wh, Wht, 1024, 4096);
  transpose_bf16<<<(1024 / 32) * (1024 / 32), 256, 0, stream>>>(W1, W1t, 1024, 1024);
  transpose_bf16<<<(1024 / 32) * (32000 / 32), 256, 0, stream>>>(W2, W2t, 1024, 32000);

  gemm_bf16<0><<<16 * 32, 256, 0, stream>>>(xbf, Wxt, bb, xg, nullptr, 2048, 4096, 512);

  lstm_kernel<<<64, 512, 0, stream>>>(xg, Wht, maskb, ench, encc, gamma, beta,
                                      mmean, mvar, hbuf32, hbn, cnt);

  gemm_bf16<1><<<16 * 8, 256, 0, stream>>>(hbn, W1t, b1, d1, nullptr, 2048, 1024, 1024);
  gemm_bf16<2><<<16 * 250, 256, 0, stream>>>(d1, W2t, b2, out, rowsum, 2048, 32000, 1024);

  rcp_kernel<<<8, 256, 0, stream>>>(rowsum);
  scale_kernel<<<2048, 256, 0, stream>>>(out, rowsum);
}